// Round 11
// baseline (512.295 us; speedup 1.0000x reference)
//
#include <hip/hip_runtime.h>
#include <math.h>

#define B_ 64
#define L_ 512
#define C_ 256
#define H_ 4
#define LAY 3
#define NEGV -1e9f

typedef __attribute__((ext_vector_type(8))) short short8;
typedef __attribute__((ext_vector_type(4))) short short4v;
typedef __attribute__((ext_vector_type(4))) float floatx4;

static __device__ __forceinline__ float rcp_(float x) { return __builtin_amdgcn_rcpf(x); }
static __device__ __forceinline__ float sig_(float x) { return rcp_(1.f + __expf(-x)); }
static __device__ __forceinline__ float tanh_(float x) {
    float e = __expf(2.f * x);
    return 1.f - 2.f * rcp_(e + 1.f);
}

static __device__ __forceinline__ short f2bf(float f) {
    unsigned x = __float_as_uint(f);
    x += 0x7fffu + ((x >> 16) & 1u);       // round-to-nearest-even to bf16
    return (short)(x >> 16);
}
static __device__ __forceinline__ float bf2f(short s) {
    return __uint_as_float(((unsigned)(unsigned short)s) << 16);
}

// XCD-aligned token swizzle for elementwise consumers (matches GEMM rb%8 = XCD).
static __device__ __forceinline__ int tok_swizzle(int blk) {
    int c8 = blk & 7, i = blk >> 3;
    return (c8 + 8 * (i >> 5)) * 128 + (i & 31) * 4;
}

static __device__ __forceinline__ void gl_lds16(const short* g, short* l) {
    __builtin_amdgcn_global_load_lds(
        (const __attribute__((address_space(1))) unsigned int*)g,
        (__attribute__((address_space(3))) unsigned int*)l, 16, 0, 0);
}

#define CF() asm volatile("" ::: "memory")

// ---------------- merged weight prep + output zeroing (1 dispatch) ----------------
#define PR_N0 (3 * 640 * 256)
#define PR_N1 (3 * 256 * 512)
#define PR_N2 (3 * 1024 * 512)
#define PR_N3 (3 * 1024)
#define PR_N4 (B_ * 70)
#define PR_TOT (PR_N0 + PR_N1 + PR_N2 + PR_N3 + PR_N4)

__global__ void prep_all(const float* __restrict__ gpW, const float* __restrict__ gfW,
                         const float* __restrict__ gpas, const float* __restrict__ gpad,
                         const float* __restrict__ gfas, const float* __restrict__ gfad,
                         const float* __restrict__ msgW,
                         const float* __restrict__ Wih, const float* __restrict__ Whh,
                         const float* __restrict__ bih, const float* __restrict__ bhh,
                         short* __restrict__ Wc, short* __restrict__ msgWb,
                         short* __restrict__ Bc, float* __restrict__ bias4,
                         float* __restrict__ outz) {
    int i = blockIdx.x * 256 + threadIdx.x;
    if (i < PR_N0) {
        int k = i & 255;
        int r = (i >> 8) % 640;
        int l = i / (640 * 256);
        float v = 0.f;
        if (r < 256) {
            v = gpW[((size_t)l * 256 + r) * 256 + k];
        } else if (r < 512) {
            v = gfW[((size_t)l * 256 + (r - 256)) * 256 + k];
        } else {
            int n = r - 512;
            if (n < 16) {
                int type = n >> 3, dir = (n >> 2) & 1, hh = n & 3;
                const float* a = type ? (dir ? gfad : gpad) : (dir ? gfas : gpas);
                const float* W = dir ? gfW : gpW;
                for (int j = 0; j < 64; j++) {
                    float av = a[l * 256 + hh * 64 + j];
                    float wv = W[((size_t)l * 256 + hh * 64 + j) * 256 + k];
                    v = fmaf(av, wv, v);
                }
            }
        }
        Wc[i] = f2bf(v);
        return;
    }
    i -= PR_N0;
    if (i < PR_N1) { msgWb[i] = f2bf(msgW[i]); return; }
    i -= PR_N1;
    if (i < PR_N2) {
        int k = i & 511, np = (i >> 9) & 1023, l = i >> 19;
        int ch = np >> 2, g = np & 3;
        float v = 0.f;
        if (g < 2) {
            v = (k < 256) ? Wih[((size_t)l * 768 + g * 256 + ch) * 256 + k]
                          : Whh[((size_t)l * 768 + g * 256 + ch) * 256 + (k - 256)];
        } else if (g == 2) {
            if (k < 256) v = Wih[((size_t)l * 768 + 512 + ch) * 256 + k];
        } else {
            if (k >= 256) v = Whh[((size_t)l * 768 + 512 + ch) * 256 + (k - 256)];
        }
        Bc[i] = f2bf(v);
        return;
    }
    i -= PR_N2;
    if (i < PR_N3) {
        int np = i & 1023, l = i >> 10;
        int ch = np >> 2, g = np & 3;
        float v;
        if (g < 2)       v = bih[l * 768 + g * 256 + ch] + bhh[l * 768 + g * 256 + ch];
        else if (g == 2) v = bih[l * 768 + 512 + ch];
        else             v = bhh[l * 768 + 512 + ch];
        bias4[i] = v;
        return;
    }
    i -= PR_N3;
    if (i < PR_N4) outz[i] = 0.f;
}

// ---------------- fused scan (64 blocks) + embed (4096 blocks x 8 tokens) ----------
__global__ __launch_bounds__(512) void scan_embed(
    const int* __restrict__ x, const float* __restrict__ emb,
    const float* __restrict__ pos, short* __restrict__ hb,
    int* __restrict__ mask, int* __restrict__ logical,
    int* __restrict__ pol, int* __restrict__ nvalid) {
    if (blockIdx.x < 64) {
        int b = blockIdx.x, t = threadIdx.x;
        __shared__ int s[L_];
        int m = (x[b * L_ + t] != 0) ? 1 : 0;
        s[t] = m;
        __syncthreads();
        for (int off = 1; off < L_; off <<= 1) {
            int v = (t >= off) ? s[t - off] : 0;
            __syncthreads();
            s[t] += v;
            __syncthreads();
        }
        int cum = s[t];
        int lg = cum - 1; if (lg < 0) lg = 0;
        mask[b * L_ + t] = m;
        logical[b * L_ + t] = lg;
        if (m) pol[b * L_ + lg] = t;
        if (t == L_ - 1) nvalid[b] = cum;
    } else {
        int t = threadIdx.x & 255, sub = threadIdx.x >> 8;
        int blk2 = (blockIdx.x - 64) * 2 + sub;
        int bl = tok_swizzle(blk2) + (t >> 6);
        int lane = t & 63;
        int xv = x[bl];
        float mf = (xv != 0) ? 1.f : 0.f;
        int l = bl & (L_ - 1);
        float4 e = *(const float4*)&emb[(size_t)xv * C_ + lane * 4];
        float4 p = *(const float4*)&pos[(size_t)l * C_ + lane * 4];
        short4v hv4;
        hv4.x = f2bf((e.x + p.x * mf) * mf);
        hv4.y = f2bf((e.y + p.y * mf) * mf);
        hv4.z = f2bf((e.z + p.z * mf) * mf);
        hv4.w = f2bf((e.w + p.w * mf) * mf);
        *(short4v*)&hb[(size_t)bl * C_ + lane * 4] = hv4;
    }
}

// ---------------- deep-GEMM fragment helpers (shared) ----------
static __device__ __forceinline__ short8 lds_rd8(const short* p) {
    return *(const short8*)p;
}

template <int MH>
static __device__ __forceinline__ void ld_af(const short* bufA, int wm, int q, int t16,
                                             short8 af[4][2]) {
#pragma unroll
    for (int mfl = 0; mfl < 4; ++mfl) {
        int row = wm * 128 + (MH * 4 + mfl) * 16 + t16;
#pragma unroll
        for (int ks = 0; ks < 2; ++ks) {
            int cg = (ks * 4 + q) ^ (row & 7);
            af[mfl][ks] = lds_rd8(&bufA[row * 64 + cg * 8]);
        }
    }
}

template <int NH>
static __device__ __forceinline__ void ld_bf(const short* bufB, int wn, int q, int t16,
                                             short8 bf[2][2]) {
#pragma unroll
    for (int nfl = 0; nfl < 2; ++nfl) {
        int row = wn * 64 + (NH * 2 + nfl) * 16 + t16;
#pragma unroll
        for (int ks = 0; ks < 2; ++ks) {
            int cg = (ks * 4 + q) ^ (row & 7);
            bf[nfl][ks] = lds_rd8(&bufB[row * 64 + cg * 8]);
        }
    }
}

// B fragment read for BN=128 (wave covers 32 cols): rows wn*32 + nfl*16 + t16
static __device__ __forceinline__ void ld_bf32(const short* bufB, int wn, int q, int t16,
                                               short8 bf[2][2]) {
#pragma unroll
    for (int nfl = 0; nfl < 2; ++nfl) {
        int row = wn * 32 + nfl * 16 + t16;
#pragma unroll
        for (int ks = 0; ks < 2; ++ks) {
            int cg = (ks * 4 + q) ^ (row & 7);
            bf[nfl][ks] = lds_rd8(&bufB[row * 64 + cg * 8]);
        }
    }
}

template <int MH, int NH>
static __device__ __forceinline__ void mfma_q(const short8 af[4][2], const short8 bf[2][2],
                                              floatx4 acc[4][8]) {
    __builtin_amdgcn_s_setprio(1);
#pragma unroll
    for (int ks = 0; ks < 2; ++ks)
#pragma unroll
        for (int mfl = 0; mfl < 4; ++mfl)
#pragma unroll
            for (int nfl = 0; nfl < 2; ++nfl)
                acc[NH * 2 + nfl][MH * 4 + mfl] = __builtin_amdgcn_mfma_f32_16x16x32_bf16(
                    bf[nfl][ks], af[mfl][ks], acc[NH * 2 + nfl][MH * 4 + mfl], 0, 0, 0);
    __builtin_amdgcn_s_setprio(0);
}

template <int MH>
static __device__ __forceinline__ void mfma_m(const short8 af[4][2], const short8 bf[2][2],
                                              floatx4 acc[2][8]) {
    __builtin_amdgcn_s_setprio(1);
#pragma unroll
    for (int ks = 0; ks < 2; ++ks)
#pragma unroll
        for (int mfl = 0; mfl < 4; ++mfl)
#pragma unroll
            for (int nfl = 0; nfl < 2; ++nfl)
                acc[nfl][MH * 4 + mfl] = __builtin_amdgcn_mfma_f32_16x16x32_bf16(
                    bf[nfl][ks], af[mfl][ks], acc[nfl][MH * 4 + mfl], 0, 0, 0);
    __builtin_amdgcn_s_setprio(0);
}

// ---- aggmsg helpers: BM=128 x BN=256, wave tile 64x64 ----
template <int MH>
static __device__ __forceinline__ void ld_afm(const short* bufA, int wm, int q, int t16,
                                              short8 af[2][2]) {
#pragma unroll
    for (int mfl = 0; mfl < 2; ++mfl) {
        int row = wm * 64 + (MH * 2 + mfl) * 16 + t16;
#pragma unroll
        for (int ks = 0; ks < 2; ++ks) {
            int cg = (ks * 4 + q) ^ (row & 7);
            af[mfl][ks] = lds_rd8(&bufA[row * 64 + cg * 8]);
        }
    }
}

static __device__ __forceinline__ void ld_bfq4(const short* bufB, int wn, int q, int t16,
                                               short8 bf[4][2]) {
#pragma unroll
    for (int nf = 0; nf < 4; ++nf) {
        int row = wn * 64 + nf * 16 + t16;
#pragma unroll
        for (int ks = 0; ks < 2; ++ks) {
            int cg = (ks * 4 + q) ^ (row & 7);
            bf[nf][ks] = lds_rd8(&bufB[row * 64 + cg * 8]);
        }
    }
}

template <int MH>
static __device__ __forceinline__ void mfma_am(const short8 af[2][2], const short8 bf[4][2],
                                               floatx4 acc[4][4]) {
    __builtin_amdgcn_s_setprio(1);
#pragma unroll
    for (int ks = 0; ks < 2; ++ks)
#pragma unroll
        for (int mfl = 0; mfl < 2; ++mfl)
#pragma unroll
            for (int nf = 0; nf < 4; ++nf)
                acc[nf][MH * 2 + mfl] = __builtin_amdgcn_mfma_f32_16x16x32_bf16(
                    bf[nf][ks], af[mfl][ks], acc[nf][MH * 2 + mfl], 0, 0, 0);
    __builtin_amdgcn_s_setprio(0);
}

// ---------------- projection + Ssd GEMM, deep 256x128 pipeline ----------
__global__ __launch_bounds__(512, 2) void projssd_deep(const short* __restrict__ A0,
                                                       const short* __restrict__ Bw,
                                                       short* __restrict__ hpb2,
                                                       float* __restrict__ Ssd) {
    __shared__ short lds[2][24576];   // per buf: A[256][64] @0, B[128][64] @16384
    const int id = blockIdx.x;
    const int j = id >> 3;                       // 0..79
    const int cb = j >> 4;                       // 0..4
    const int rb = (id & 7) * 16 + (j & 15);     // 0..127
    const int tid = threadIdx.x;
    const int wave = tid >> 6, lane = tid & 63;
    const int wm = wave >> 2, wn = wave & 3;
    const int q = lane >> 4, t16 = lane & 15;
    const size_t arow0 = (size_t)rb * 256;
    const short* Bb = Bw + (size_t)cb * 128 * 256;

    floatx4 acc[2][8];
#pragma unroll
    for (int i = 0; i < 2; i++)
#pragma unroll
        for (int jj = 0; jj < 8; jj++) acc[i][jj] = (floatx4)0.f;

    auto stageA = [&](int t, int Hh) {
        short* bufA = lds[t & 1];
#pragma unroll
        for (int u = 0; u < 2; ++u) {
            int unit = u * 512 + tid;
            int row = Hh * 128 + (unit >> 3);
            int cs = (unit & 7) ^ (row & 7);
            gl_lds16(A0 + (arow0 + (size_t)row) * 256 + t * 64 + cs * 8,
                     bufA + Hh * 8192 + unit * 8);
        }
    };
    auto stageB = [&](int t) {
        short* bufB = lds[t & 1] + 16384;
#pragma unroll
        for (int u = 0; u < 2; ++u) {
            int unit = u * 512 + tid;
            int row = unit >> 3;                 // 0..127
            int cs = (unit & 7) ^ (row & 7);
            gl_lds16(Bb + (size_t)row * 256 + t * 64 + cs * 8, bufB + unit * 8);
        }
    };

    stageA(0, 0); stageA(0, 1); stageB(0); stageB(1);
    asm volatile("s_waitcnt vmcnt(2)" ::: "memory");
    CF(); __builtin_amdgcn_s_barrier(); CF();

    short8 af[4][2], bfr[2][2];

#pragma unroll
    for (int t = 0; t < 4; ++t) {
        const short* bufA = lds[t & 1];
        const short* bufB = lds[t & 1] + 16384;

        ld_af<0>(bufA, wm, q, t16, af);
        ld_bf32(bufB, wn, q, t16, bfr);
        if (t < 3) { stageA(t + 1, 0); stageA(t + 1, 1); }
        CF(); __builtin_amdgcn_s_barrier();
        asm volatile("s_waitcnt lgkmcnt(0)" ::: "memory");
        __builtin_amdgcn_sched_barrier(0);
        mfma_m<0>(af, bfr, acc);
        CF(); __builtin_amdgcn_s_barrier(); CF();

        ld_af<1>(bufA, wm, q, t16, af);
        if (t < 2) stageB(t + 2);
        CF(); __builtin_amdgcn_s_barrier();
        asm volatile("s_waitcnt lgkmcnt(0)" ::: "memory");
        __builtin_amdgcn_sched_barrier(0);
        mfma_m<1>(af, bfr, acc);
        if (t < 2)       asm volatile("s_waitcnt vmcnt(2)" ::: "memory");
        else if (t == 2) asm volatile("s_waitcnt vmcnt(0)" ::: "memory");
        CF(); __builtin_amdgcn_s_barrier(); CF();
    }

    if (cb < 4) {
        short* sO = (short*)lds;                 // [256][132]
#pragma unroll
        for (int nf = 0; nf < 2; nf++) {
            int chl = wn * 32 + nf * 16 + q * 4; // 0..127 within block
#pragma unroll
            for (int mf = 0; mf < 8; mf++) {
                int rowl = wm * 128 + mf * 16 + t16;
                short4v pk;
                pk.x = f2bf(acc[nf][mf][0]);
                pk.y = f2bf(acc[nf][mf][1]);
                pk.z = f2bf(acc[nf][mf][2]);
                pk.w = f2bf(acc[nf][mf][3]);
                *(short4v*)&sO[rowl * 132 + chl] = pk;
            }
        }
        __syncthreads();
#pragma unroll
        for (int it = 0; it < 8; ++it) {
            int unit = it * 512 + tid;
            int rowl = unit >> 4, ck = unit & 15;
            *(short8*)&hpb2[(arow0 + rowl) * 512 + cb * 128 + ck * 8] =
                *(const short8*)&sO[rowl * 132 + ck * 8];
        }
    } else {
        if (wn == 0) {
            int chl = q * 4;
            if (chl < 16) {
#pragma unroll
                for (int mf = 0; mf < 8; mf++) {
                    int rowl = wm * 128 + mf * 16 + t16;
                    float4 pk = make_float4(acc[0][mf][0], acc[0][mf][1],
                                            acc[0][mf][2], acc[0][mf][3]);
                    *(float4*)&Ssd[(arow0 + rowl) * 16 + chl] = pk;
                }
            }
        }
    }
}

// ---------------- dedicated GRU GEMM, 256x256 tile, 8-phase deep-vmcnt ----------
// (measured-good: BK=64, 1 block/CU, full unroll + sched_barrier, vmcnt(8))
__global__ __launch_bounds__(512, 2) void gru_bgemm(const short* __restrict__ mmb,
                                                    const short* __restrict__ hb_in,
                                                    const short* __restrict__ Bw,
                                                    short* __restrict__ hn2b,
                                                    const float* __restrict__ bias4) {
    __shared__ short lds[2][32768];   // per buf: A[256][64] @0, B[256][64] @16384
    const int id = blockIdx.x;
    const int rb = 16 * (id & 7) + (id >> 5);
    const int cb = (id >> 3) & 3;
    const int tid = threadIdx.x;
    const int wave = tid >> 6, lane = tid & 63;
    const int wm = wave >> 2, wn = wave & 3;
    const int q = lane >> 4, t16 = lane & 15;
    const size_t arow0 = (size_t)rb * 256;
    const short* Bb = Bw + (size_t)cb * 256 * 512;
    const int ord0 = (5 + cb) & 7;

    floatx4 acc[4][8];   // [nf][mf]
#pragma unroll
    for (int i = 0; i < 4; i++)
#pragma unroll
        for (int jj = 0; jj < 8; jj++) acc[i][jj] = (floatx4)0.f;

    auto stageA = [&](int i, int Hh) {
        int tt = (ord0 + i) & 7;
        const short* Asrc = (tt < 4) ? (mmb + tt * 64) : (hb_in + (tt - 4) * 64);
        short* bufA = lds[i & 1];
#pragma unroll
        for (int u = 0; u < 2; ++u) {
            int unit = u * 512 + tid;              // 0..1023
            int row = Hh * 128 + (unit >> 3);
            int cs = (unit & 7) ^ (row & 7);
            gl_lds16(Asrc + (arow0 + (size_t)row) * 256 + cs * 8,
                     bufA + Hh * 8192 + unit * 8);
        }
    };
    auto stageB = [&](int i, int Hh) {
        int tt = (ord0 + i) & 7;
        short* bufB = lds[i & 1] + 16384;
#pragma unroll
        for (int u = 0; u < 2; ++u) {
            int unit = u * 512 + tid;
            int row = Hh * 128 + (unit >> 3);
            int cs = (unit & 7) ^ (row & 7);
            gl_lds16(Bb + (size_t)row * 512 + tt * 64 + cs * 8,
                     bufB + Hh * 8192 + unit * 8);
        }
    };

    // prologue: tiles 0 and 1 fully issued (16 loads/wave);
    // vmcnt(8): tile 0 complete, tile 1's 8 loads stay in flight
    stageA(0, 0); stageA(0, 1); stageB(0, 0); stageB(0, 1);
    stageA(1, 0); stageA(1, 1); stageB(1, 0); stageB(1, 1);
    asm volatile("s_waitcnt vmcnt(8)" ::: "memory");
    CF(); __builtin_amdgcn_s_barrier(); CF();

    short8 af[4][2], b0[2][2], b1[2][2];

#pragma unroll
    for (int t = 0; t < 8; ++t) {
        const short* bufA = lds[t & 1];
        const short* bufB = lds[t & 1] + 16384;

        // ---- P0: quadrant (0,0) ----
        ld_af<0>(bufA, wm, q, t16, af);
        ld_bf<0>(bufB, wn, q, t16, b0);
        CF(); __builtin_amdgcn_s_barrier();
        asm volatile("s_waitcnt lgkmcnt(0)" ::: "memory");
        __builtin_amdgcn_sched_barrier(0);
        mfma_q<0, 0>(af, b0, acc);
        CF(); __builtin_amdgcn_s_barrier(); CF();

        // ---- P1: quadrant (0,1) ----
        ld_bf<1>(bufB, wn, q, t16, b1);
        CF(); __builtin_amdgcn_s_barrier();
        asm volatile("s_waitcnt lgkmcnt(0)" ::: "memory");
        __builtin_amdgcn_sched_barrier(0);
        mfma_q<0, 1>(af, b1, acc);
        CF(); __builtin_amdgcn_s_barrier(); CF();

        // ---- P2: quadrant (1,1) ----  (bufB[t&1] free after P1's end barrier)
        ld_af<1>(bufA, wm, q, t16, af);
        if (t < 6) { stageB(t + 2, 0); stageB(t + 2, 1); }
        CF(); __builtin_amdgcn_s_barrier();
        asm volatile("s_waitcnt lgkmcnt(0)" ::: "memory");
        __builtin_amdgcn_sched_barrier(0);
        mfma_q<1, 1>(af, b1, acc);
        CF(); __builtin_amdgcn_s_barrier(); CF();

        // ---- P3: quadrant (1,0) ----  (bufA[t&1] free after P2's end barrier)
        if (t < 6) { stageA(t + 2, 0); stageA(t + 2, 1); }
        CF(); __builtin_amdgcn_s_barrier();
        mfma_q<1, 0>(af, b0, acc);
        // tile boundary: su(t+1) (oldest 8) complete; su(t+2) (8) stay in flight
        if (t < 6)       asm volatile("s_waitcnt vmcnt(8)" ::: "memory");
        else if (t == 6) asm volatile("s_waitcnt vmcnt(0)" ::: "memory");
        CF(); __builtin_amdgcn_s_barrier(); CF();
    }

    // epilogue: h_prev from LDS (lds[1] holds A-tile of tt=4+cb = hb cols cb*64..),
    // compute gates, stage hn2 tile in LDS, coalesced bf16 write.
    const short* hpt = lds[1];
    short* sO = (short*)lds;                   // [256][72] bf16 within lds[0]
#pragma unroll
    for (int nf = 0; nf < 4; nf++) {
        int chl = wn * 16 + nf * 4 + q;        // 0..63 within block
        int col0 = cb * 256 + wn * 64 + nf * 16 + q * 4;
        float4 bv4 = *(const float4*)&bias4[col0];
#pragma unroll
        for (int mf = 0; mf < 8; mf++) {
            int rowl = wm * 128 + mf * 16 + t16;
            float hp = bf2f(hpt[rowl * 64 + (((chl >> 3) ^ (rowl & 7)) << 3) + (chl & 7)]);
            float r = sig_(acc[nf][mf][0] + bv4.x);
            float z = sig_(acc[nf][mf][1] + bv4.y);
            float nv = tanh_((acc[nf][mf][2] + bv4.z) + r * (acc[nf][mf][3] + bv4.w));
            sO[rowl * 72 + chl] = f2bf((1.f - z) * nv + z * hp);
        }
    }
    __syncthreads();
#pragma unroll
    for (int it = 0; it < 4; ++it) {
        int unit = it * 512 + tid;
        int rowl = unit >> 3, ck = unit & 7;
        *(short8*)&hn2b[(arow0 + rowl) * 256 + cb * 64 + ck * 8] =
            *(const short8*)&sO[rowl * 72 + ck * 8];
    }
}

// ---------------- fused GAT-aggregate + msg GEMM ----------------
// C = relu(AGG(hpb2) @ msgWb^T + bias) -> bf16 mmb [32768,256], without
// materializing mb. BM=128 x BN=256, K=512 (8 tiles of 64), grid 256 = 1/CU.
// Per K-tile the (dir,head) pair is constant -> each A-row needs ONE softmax
// weight-set (4 w, 3 neighbor tokens) + 4 gathered short8 per 8-col unit.
// A(t+1) computed in P0(t) into As[(t+1)&1] (free since P1(t-1) barrier);
// ds_writes drained by P0's lgkmcnt(0) + end barrier before P0(t+1) reads.
// B double-buffered via global_load_lds (4 loads/stage), deep vmcnt(4).
// Weight formulas copied verbatim from the verified agg_fused.
__global__ __launch_bounds__(512, 2) void aggmsg_bgemm(
    const short* __restrict__ hpb2, const float* __restrict__ S,
    const int* __restrict__ mask, const int* __restrict__ logical,
    const int* __restrict__ pol, const int* __restrict__ nvalid,
    const short* __restrict__ Bw, short* __restrict__ Cout,
    const float* __restrict__ bias, int dil) {
    __shared__ short lds[49152];   // As0@0, As1@8192, Bs0@16384, Bs1@32768 (shorts)
    __shared__ int jsm[128][8];    // per row: js dir0[3], js dir1[3], mi
    const int id = blockIdx.x;
    const int rb = (id & 7) * 32 + (id >> 3);    // 0..255, XCD-contiguous
    const int tid = threadIdx.x;
    const int wave = tid >> 6, lane = tid & 63;
    const int wm = wave >> 2, wn = wave & 3;
    const int q = lane >> 4, t16 = lane & 15;
    const int arow0 = rb * 128;
    const int b = arow0 >> 9;                    // uniform per block

    floatx4 acc[4][4];
#pragma unroll
    for (int i = 0; i < 4; i++)
#pragma unroll
        for (int jj = 0; jj < 4; jj++) acc[i][jj] = (floatx4)0.f;

    auto stageB = [&](int t) {
        short* bufB = lds + 16384 + (t & 1) * 16384;
#pragma unroll
        for (int u = 0; u < 4; ++u) {
            int unit = u * 512 + tid;            // 0..2047 -> row 0..255
            int row = unit >> 3;
            int cs = (unit & 7) ^ (row & 7);
            gl_lds16(Bw + (size_t)row * 512 + t * 64 + cs * 8, bufB + unit * 8);
        }
    };

    auto computeA = [&](int tt) {
        short* bufA = lds + (tt & 1) * 8192;
        int dir = tt >> 2, head = tt & 3;
        int sn = dir * 4 + head, dn = 8 + sn;
        int doff = dir * 256 + head * 64;
#pragma unroll
        for (int i = 0; i < 2; ++i) {
            int unit = i * 512 + tid;            // 0..1023 -> row 0..127
            int row = unit >> 3, cb8 = unit & 7;
            int j0 = jsm[row][dir * 3 + 0];
            int j1 = jsm[row][dir * 3 + 1];
            int j2 = jsm[row][dir * 3 + 2];
            int tok = arow0 + row;
            float si = S[(size_t)tok * 16 + sn];
            float di = S[(size_t)tok * 16 + dn];
            float e0 = si + di; e0 = e0 > 0.f ? e0 : 0.2f * e0;
            float e1 = -1e30f, e2 = -1e30f, e3 = -1e30f;
            if (j0 >= 0) { float e = si + S[(size_t)j0 * 16 + dn]; e1 = e > 0.f ? e : 0.2f * e; }
            if (j1 >= 0) { float e = si + S[(size_t)j1 * 16 + dn]; e2 = e > 0.f ? e : 0.2f * e; }
            if (j2 >= 0) { float e = si + S[(size_t)j2 * 16 + dn]; e3 = e > 0.f ? e : 0.2f * e; }
            float emax = fmaxf(fmaxf(e0, e1), fmaxf(e2, e3));
            float w0 = __expf(e0 - emax);
            float w1 = (j0 >= 0) ? __expf(e1 - emax) : 0.f;
            float w2 = (j1 >= 0) ? __expf(e2 - emax) : 0.f;
            float w3 = (j2 >= 0) ? __expf(e3 - emax) : 0.f;
            float rden = rcp_(((w0 + w1) + (w2 + w3)));
            size_t cboff = (size_t)doff + cb8 * 8;
            short8 v0 = *(const short8*)&hpb2[(size_t)tok * 512 + cboff];
            float o[8];
#pragma unroll
            for (int jj = 0; jj < 8; jj++) o[jj] = w0 * bf2f(v0[jj]);
            if (j0 >= 0) {
                short8 vn = *(const short8*)&hpb2[(size_t)j0 * 512 + cboff];
#pragma unroll
                for (int jj = 0; jj < 8; jj++) o[jj] = fmaf(w1, bf2f(vn[jj]), o[jj]);
            }
            if (j1 >= 0) {
                short8 vn = *(const short8*)&hpb2[(size_t)j1 * 512 + cboff];
#pragma unroll
                for (int jj = 0; jj < 8; jj++) o[jj] = fmaf(w2, bf2f(vn[jj]), o[jj]);
            }
            if (j2 >= 0) {
                short8 vn = *(const short8*)&hpb2[(size_t)j2 * 512 + cboff];
#pragma unroll
                for (int jj = 0; jj < 8; jj++) o[jj] = fmaf(w3, bf2f(vn[jj]), o[jj]);
            }
            short8 ov;
#pragma unroll
            for (int jj = 0; jj < 8; jj++) ov[jj] = f2bf(o[jj] * rden);
            *(short8*)&bufA[row * 64 + ((cb8 ^ (row & 7)) * 8)] = ov;
        }
    };

    // prologue: meta, B(0)+B(1) DMA, then A(0) computed
    if (tid < 128) {
        int tok = arow0 + tid;
        int mi = mask[tok];
        int li = logical[tok];
        int nv = nvalid[b];
#pragma unroll
        for (int dir = 0; dir < 2; ++dir)
#pragma unroll
            for (int k = 1; k <= 3; ++k) {
                int lj = dir ? (li - k * dil) : (li + k * dil);
                int jg = (mi && lj >= 0 && lj < nv) ? (b * L_ + pol[b * L_ + lj]) : -1;
                jsm[tid][dir * 3 + (k - 1)] = jg;
            }
        jsm[tid][6] = mi;
    }
    stageB(0); stageB(1);
    __syncthreads();                 // meta visible
    computeA(0);
    // B(0) complete (B(1)'s 4 loads in flight) + A(0) ds_writes drained
    asm volatile("s_waitcnt vmcnt(4) lgkmcnt(0)" ::: "memory");
    CF(); __builtin_amdgcn_s_barrier(); CF();

    short8 af[2][2], bfq[4][2];

#pragma unroll
    for (int t = 0; t < 8; ++t) {
        const short* bufA = lds + (t & 1) * 8192;
        const short* bufB = lds + 16384 + (t & 1) * 16384;

        // ---- P0 ----
        ld_afm<0>(bufA, wm, q, t16, af);
        ld_bfq4(bufB, wn, q, t16, bfq);
        if (t < 7) computeA(t + 1);              // As[(t+1)&1] free since P1(t-1)
        CF(); __builtin_amdgcn_s_barrier();
        asm volatile("s_waitcnt lgkmcnt(0)" ::: "memory");
        __builtin_amdgcn_sched_barrier(0);
        mfma_am<0>(af, bfq, acc);
        CF(); __builtin_amdgcn_s_barrier(); CF();

        // ---- P1 ----
        ld_afm<1>(bufA, wm, q, t16, af);
        if (t < 6) stageB(t + 2);                // Bs[t&1] free after P0 reads
        CF(); __builtin_amdgcn_s_barrier();
        asm volatile("s_waitcnt lgkmcnt(0)" ::: "memory");
        __builtin_amdgcn_sched_barrier(0);
        mfma_am<1>(af, bfq, acc);
        // boundary: B(t+1) complete; B(t+2)'s 4 loads stay in flight
        if (t < 6)       asm volatile("s_waitcnt vmcnt(4)" ::: "memory");
        else if (t == 6) asm volatile("s_waitcnt vmcnt(0)" ::: "memory");
        CF(); __builtin_amdgcn_s_barrier(); CF();
    }

    // epilogue: bias + relu + bf16, LDS-staged coalesced write (sO [128][264])
    short* sO = lds;
#pragma unroll
    for (int nf = 0; nf < 4; nf++) {
        int col0 = wn * 64 + nf * 16 + q * 4;    // 0..255
        float4 bv4 = *(const float4*)&bias[col0];
#pragma unroll
        for (int mf = 0; mf < 4; mf++) {
            int rowl = wm * 64 + mf * 16 + t16;  // 0..127
            short4v pk;
            pk.x = f2bf(fmaxf(acc[nf][mf][0] + bv4.x, 0.f));
            pk.y = f2bf(fmaxf(acc[nf][mf][1] + bv4.y, 0.f));
            pk.z = f2bf(fmaxf(acc[nf][mf][2] + bv4.z, 0.f));
            pk.w = f2bf(fmaxf(acc[nf][mf][3] + bv4.w, 0.f));
            *(short4v*)&sO[rowl * 264 + col0] = pk;
        }
    }
    __syncthreads();
    // coalesced write: 128 rows x 256 cols, short8 chunks (4096 units / 512 thr)
#pragma unroll
    for (int it = 0; it < 8; ++it) {
        int unit = it * 512 + tid;
        int rowl = unit >> 5, ck = unit & 31;
        *(short8*)&Cout[((size_t)arow0 + rowl) * 256 + ck * 8] =
            *(const short8*)&sO[rowl * 264 + ck * 8];
    }
}

// ---------------- LayerNorm over hn2 (bf16) + mask -> hb (layers 0,1 only) ------
__global__ __launch_bounds__(256) void ln_kernel(
    const short* __restrict__ hn2b, short* __restrict__ hb,
    const int* __restrict__ mask,
    const float* __restrict__ lng, const float* __restrict__ lnb) {
    int t = threadIdx.x;
    int bl = tok_swizzle(blockIdx.x) + (t >> 6);
    int lane = t & 63;
    short4v v4 = *(const short4v*)&hn2b[(size_t)bl * C_ + lane * 4];
    float v[4] = {bf2f(v4.x), bf2f(v4.y), bf2f(v4.z), bf2f(v4.w)};
    float s = (v[0] + v[1]) + (v[2] + v[3]);
    float ss = (v[0] * v[0] + v[1] * v[1]) + (v[2] * v[2] + v[3] * v[3]);
#pragma unroll
    for (int off = 32; off; off >>= 1) {
        s += __shfl_xor(s, off);
        ss += __shfl_xor(ss, off);
    }
    float mu = s * (1.f / 256.f);
    float var = ss * (1.f / 256.f) - mu * mu;
    float rstd = rsqrtf(fmaxf(var, 0.f) + 1e-5f);
    float4 lg = *(const float4*)&lng[lane * 4];
    float4 lb = *(const float4*)&lnb[lane * 4];
    float mfv = mask[bl] ? 1.f : 0.f;
    short4v yb;
    yb.x = f2bf(((v[0] - mu) * rstd * lg.x + lb.x) * mfv);
    yb.y = f2bf(((v[1] - mu) * rstd * lg.y + lb.y) * mfv);
    yb.z = f2bf(((v[2] - mu) * rstd * lg.z + lb.z) * mfv);
    yb.w = f2bf(((v[3] - mu) * rstd * lg.w + lb.w) * mfv);
    *(short4v*)&hb[(size_t)bl * C_ + lane * 4] = yb;
}

// ---------------- pooling + heads with layer-2 LN folded in ----------------
__global__ __launch_bounds__(1024) void pool_head_ln(
    const short* __restrict__ hn2b, const int* __restrict__ mask,
    const float* __restrict__ pw, const float* __restrict__ pb,
    const float* __restrict__ lng2, const float* __restrict__ lnb2,
    const float* __restrict__ h0W, const float* __restrict__ h0b,
    const float* __restrict__ h1W, const float* __restrict__ h1b,
    float* __restrict__ out) {
    int b = blockIdx.x >> 2, s = blockIdx.x & 3;
    int t = threadIdx.x;
    int lane = t & 63, wave = t >> 6;
    __shared__ float sc[L_];
    __shared__ float muA[L_];
    __shared__ float rsA[L_];
    __shared__ float red[24];
    __shared__ float part[16][64];
    __shared__ float pooled[64];

    float4 wv = *(const float4*)&pw[lane * 4];
    float4 gv = *(const float4*)&lng2[lane * 4];
    float4 bv = *(const float4*)&lnb2[lane * 4];
    float pg0 = wv.x * gv.x, pg1 = wv.y * gv.y, pg2 = wv.z * gv.z, pg3 = wv.w * gv.w;
    float cG = (pg0 + pg1) + (pg2 + pg3);
    float cB = (wv.x * bv.x + wv.y * bv.y) + (wv.z * bv.z + wv.w * bv.w);
#pragma unroll
    for (int off = 32; off; off >>= 1) {
        cG += __shfl_xor(cG, off);
        cB += __shfl_xor(cB, off);
    }
    float pb0 = pb[0];

    // pass 1: per-row score + LN stats
    for (int l = wave; l < L_; l += 16) {
        short4v hv = *(const short4v*)&hn2b[((size_t)b * L_ + l) * C_ + lane * 4];
        float h0 = bf2f(hv.x), h1 = bf2f(hv.y), h2 = bf2f(hv.z), h3 = bf2f(hv.w);
        float s1 = pg0 * h0 + pg1 * h1 + pg2 * h2 + pg3 * h3;
        float s2 = (h0 + h1) + (h2 + h3);
        float s3 = (h0 * h0 + h1 * h1) + (h2 * h2 + h3 * h3);
#pragma unroll
        for (int off = 32; off; off >>= 1) {
            s1 += __shfl_down(s1, off);
            s2 += __shfl_down(s2, off);
            s3 += __shfl_down(s3, off);
        }
        if (lane == 0) {
            float mu = s2 * (1.f / 256.f);
            float var = s3 * (1.f / 256.f) - mu * mu;
            float rstd = rsqrtf(fmaxf(var, 0.f) + 1e-5f);
            int mk = mask[b * L_ + l];
            sc[l] = mk ? (rstd * (s1 - mu * cG) + cB + pb0) : NEGV;
            muA[l] = mu;
            rsA[l] = mk ? rstd : 0.f;
        }
    }
    __syncthreads();

    // softmax over 512 scores
    float v = (t < L_) ? sc[t] : NEGV;
    float mx = v;
#pragma unroll
    for (int off = 32; off; off >>= 1) mx = fmaxf(mx, __shfl_down(mx, off));
    if (lane == 0) red[wave] = mx;
    __syncthreads();
    if (t == 0) {
        float g = red[0];
        for (int i = 1; i < 16; i++) g = fmaxf(g, red[i]);
        red[16] = g;
    }
    __syncthreads();
    float gmax = red[16];
    float e = (t < L_) ? __expf(v - gmax) : 0.f;
    float ssum = e;
#pragma unroll
    for (int off = 32; off; off >>= 1) ssum += __shfl_down(ssum, off);
    if (lane == 0) red[wave] = ssum;
    __syncthreads();
    if (t == 0) {
        float g = 0.f;
        for (int i = 0; i < 16; i++) g += red[i];
        red[17] = 1.f / g;
    }
    __syncthreads();
    float a = e * red[17];
    float arv = (t < L_) ? a * rsA[t] : 0.f;
    float amu = (t < L_) ? arv * muA[t] : 0.f;
    if (t < L_) sc[t] = arv;
#pragma unroll
    for (int off = 32; off; off >>= 1) amu += __shfl_down(amu, off);
    if (lane == 0) red[wave] = amu;
    __syncthreads();
    if (t == 0) {
        float g = 0.f;
        for (int i = 0; i < 16; i++) g += red[i];
        red[18] = g;
    }
    __syncthreads();

    // pass 2: weighted raw sum over this block's 64-ch slice, then LN transform
    {
        int c0 = t & 63, lw = t >> 6;
        const short* hcol = &hn2b[((size_t)b * L_ + lw * 32) * C_ + s * 64 + c0];
        const float* scg = &sc[lw * 32];
        float a0 = 0.f, a1 = 0.f;
        for (int l = 0; l < 32; l += 2) {
            a0 = fmaf(scg[l + 0], bf2f(hcol[(size_t)(l + 0) * C_]), a0);
            a1 = fmaf(scg[l + 1], bf2f(hcol[(size_t)(l + 1) * C_]), a1);
        }
        part[lw][c0] = a0 + a1;
    }
    __syncthreads();
    if (t < 64) {
        float p = 0.f;
        for (int i = 0; i < 16; i++) p += part[i][t];
        int c = s * 64 + t;
        pooled[t] = lng2[c] * (p - red[18]) + lnb2[c];
    }
    __syncthreads();

    // pass 3: head partials over this 64-ch slice, atomicAdd to out
    for (int o = wave; o < 70; o += 16) {
        const float* W = (o < 50) ? (h0W + (size_t)o * C_) : (h1W + (size_t)(o - 50) * C_);
        float sv = pooled[lane] * W[s * 64 + lane];
#pragma unroll
        for (int off = 32; off; off >>= 1) sv += __shfl_down(sv, off);
        if (lane == 0) {
            float add = sv + ((s == 0) ? ((o < 50) ? h0b[o] : h1b[o - 50]) : 0.f);
            atomicAdd(&out[b * 70 + o], add);
        }
    }
}

extern "C" void kernel_launch(void* const* d_in, const int* in_sizes, int n_in,
                              void* d_out, int out_size, void* d_ws, size_t ws_size,
                              hipStream_t stream) {
    const int*   x    = (const int*)d_in[0];
    const float* emb  = (const float*)d_in[1];
    const float* pos  = (const float*)d_in[2];
    const float* gpW  = (const float*)d_in[3];
    const float* gpas = (const float*)d_in[4];
    const float* gpad = (const float*)d_in[5];
    const float* gfW  = (const float*)d_in[6];
    const float* gfas = (const float*)d_in[7];
    const float* gfad = (const float*)d_in[8];
    const float* msgW = (const float*)d_in[9];
    const float* msgb = (const float*)d_in[10];
    const float* Wih  = (const float*)d_in[11];
    const float* bih  = (const float*)d_in[12];
    const float* Whh  = (const float*)d_in[13];
    const float* bhh  = (const float*)d_in[14];
    const float* lng  = (const float*)d_in[15];
    const float* lnb  = (const float*)d_in[16];
    const float* pw   = (const float*)d_in[17];
    const float* pb   = (const float*)d_in[18];
    const float* h0W  = (const float*)d_in[19];
    const float* h0b  = (const float*)d_in[20];
    const float* h1W  = (const float*)d_in[21];
    const float* h1b  = (const float*)d_in[22];
    float* out = (float*)d_out;

    const size_t MW = 1024 * 1024;
    float* ws = (float*)d_ws;
    short* hn2b = (short*)ws;
    short* hb   = (short*)(ws + 8 * MW);
    short* mmb  = (short*)(ws + 12 * MW);
    float* Ssd  = ws + 12 * MW;                          // aliases mmb (timeshared)
    short* hpb2 = (short*)(ws + 16 * MW);
    short* Wcomb = (short*)(ws + 32 * MW);               // 3*640*256 shorts
    short* msgWb = Wcomb + 3 * 640 * 256;                // 3*256*512 shorts
    short* Bcat  = msgWb + 3 * 256 * 512;                // 3*1024*512 shorts (interleaved)
    float* bias4 = (float*)(Bcat + 3 * 1024 * 512);      // 3*1024 floats
    int* mask    = (int*)(bias4 + 3 * 1024);
    int* logical = mask + B_ * L_;
    int* pol     = logical + B_ * L_;
    int* nvalid  = pol + B_ * L_;

    prep_all<<<(PR_TOT + 255) / 256, 256, 0, stream>>>(
        gpW, gfW, gpas, gpad, gfas, gfad, msgW, Wih, Whh, bih, bhh,
        Wcomb, msgWb, Bcat, bias4, out);

    scan_embed<<<64 + 4096, 512, 0, stream>>>(x, emb, pos, hb, mask, logical, pol, nvalid);

    const int DILS[LAY] = {1, 2, 4};

    for (int l = 0; l < LAY; l++) {
        int dil = DILS[l];
        projssd_deep<<<640, 512, 0, stream>>>(hb, Wcomb + (size_t)l * 640 * 256,
                                              hpb2, Ssd);
        // fused GAT-aggregate + msg GEMM -> mmb (replaces agg_fused + msg_bgemm)
        aggmsg_bgemm<<<256, 512, 0, stream>>>(hpb2, Ssd, mask, logical, pol, nvalid,
                                              msgWb + (size_t)l * 256 * 512,
                                              mmb, msgb + l * C_, dil);
        gru_bgemm<<<512, 512, 0, stream>>>(mmb, hb, Bcat + (size_t)l * 1024 * 512,
                                           hn2b, bias4 + l * 1024);
        if (l < 2)
            ln_kernel<<<8192, 256, 0, stream>>>(hn2b, hb, mask, lng + l * C_, lnb + l * C_);
    }

    pool_head_ln<<<B_ * 4, 1024, 0, stream>>>(hn2b, mask, pw, pb,
                                              lng + 2 * C_, lnb + 2 * C_,
                                              h0W, h0b, h1W, h1b, out);
}

// Round 12
// 462.640 us; speedup vs baseline: 1.1073x; 1.1073x over previous
//
#include <hip/hip_runtime.h>
#include <math.h>

#define B_ 64
#define L_ 512
#define C_ 256
#define H_ 4
#define LAY 3
#define NEGV -1e9f

typedef __attribute__((ext_vector_type(8))) short short8;
typedef __attribute__((ext_vector_type(4))) short short4v;
typedef __attribute__((ext_vector_type(4))) float floatx4;

static __device__ __forceinline__ float rcp_(float x) { return __builtin_amdgcn_rcpf(x); }
static __device__ __forceinline__ float sig_(float x) { return rcp_(1.f + __expf(-x)); }
static __device__ __forceinline__ float tanh_(float x) {
    float e = __expf(2.f * x);
    return 1.f - 2.f * rcp_(e + 1.f);
}

static __device__ __forceinline__ short f2bf(float f) {
    unsigned x = __float_as_uint(f);
    x += 0x7fffu + ((x >> 16) & 1u);       // round-to-nearest-even to bf16
    return (short)(x >> 16);
}
static __device__ __forceinline__ float bf2f(short s) {
    return __uint_as_float(((unsigned)(unsigned short)s) << 16);
}

// XCD-aligned token swizzle for elementwise consumers (matches GEMM rb%8 = XCD).
static __device__ __forceinline__ int tok_swizzle(int blk) {
    int c8 = blk & 7, i = blk >> 3;
    return (c8 + 8 * (i >> 5)) * 128 + (i & 31) * 4;
}

static __device__ __forceinline__ void gl_lds16(const short* g, short* l) {
    __builtin_amdgcn_global_load_lds(
        (const __attribute__((address_space(1))) unsigned int*)g,
        (__attribute__((address_space(3))) unsigned int*)l, 16, 0, 0);
}

#define CF() asm volatile("" ::: "memory")

// ---------------- merged weight prep + output zeroing (1 dispatch) ----------------
#define PR_N0 (3 * 640 * 256)
#define PR_N1 (3 * 256 * 512)
#define PR_N2 (3 * 1024 * 512)
#define PR_N3 (3 * 1024)
#define PR_N4 (B_ * 70)
#define PR_TOT (PR_N0 + PR_N1 + PR_N2 + PR_N3 + PR_N4)

__global__ void prep_all(const float* __restrict__ gpW, const float* __restrict__ gfW,
                         const float* __restrict__ gpas, const float* __restrict__ gpad,
                         const float* __restrict__ gfas, const float* __restrict__ gfad,
                         const float* __restrict__ msgW,
                         const float* __restrict__ Wih, const float* __restrict__ Whh,
                         const float* __restrict__ bih, const float* __restrict__ bhh,
                         short* __restrict__ Wc, short* __restrict__ msgWb,
                         short* __restrict__ Bc, float* __restrict__ bias4,
                         float* __restrict__ outz) {
    int i = blockIdx.x * 256 + threadIdx.x;
    if (i < PR_N0) {
        int k = i & 255;
        int r = (i >> 8) % 640;
        int l = i / (640 * 256);
        float v = 0.f;
        if (r < 256) {
            v = gpW[((size_t)l * 256 + r) * 256 + k];
        } else if (r < 512) {
            v = gfW[((size_t)l * 256 + (r - 256)) * 256 + k];
        } else {
            int n = r - 512;
            if (n < 16) {
                int type = n >> 3, dir = (n >> 2) & 1, hh = n & 3;
                const float* a = type ? (dir ? gfad : gpad) : (dir ? gfas : gpas);
                const float* W = dir ? gfW : gpW;
                for (int j = 0; j < 64; j++) {
                    float av = a[l * 256 + hh * 64 + j];
                    float wv = W[((size_t)l * 256 + hh * 64 + j) * 256 + k];
                    v = fmaf(av, wv, v);
                }
            }
        }
        Wc[i] = f2bf(v);
        return;
    }
    i -= PR_N0;
    if (i < PR_N1) { msgWb[i] = f2bf(msgW[i]); return; }
    i -= PR_N1;
    if (i < PR_N2) {
        int k = i & 511, np = (i >> 9) & 1023, l = i >> 19;
        int ch = np >> 2, g = np & 3;
        float v = 0.f;
        if (g < 2) {
            v = (k < 256) ? Wih[((size_t)l * 768 + g * 256 + ch) * 256 + k]
                          : Whh[((size_t)l * 768 + g * 256 + ch) * 256 + (k - 256)];
        } else if (g == 2) {
            if (k < 256) v = Wih[((size_t)l * 768 + 512 + ch) * 256 + k];
        } else {
            if (k >= 256) v = Whh[((size_t)l * 768 + 512 + ch) * 256 + (k - 256)];
        }
        Bc[i] = f2bf(v);
        return;
    }
    i -= PR_N2;
    if (i < PR_N3) {
        int np = i & 1023, l = i >> 10;
        int ch = np >> 2, g = np & 3;
        float v;
        if (g < 2)       v = bih[l * 768 + g * 256 + ch] + bhh[l * 768 + g * 256 + ch];
        else if (g == 2) v = bih[l * 768 + 512 + ch];
        else             v = bhh[l * 768 + 512 + ch];
        bias4[i] = v;
        return;
    }
    i -= PR_N3;
    if (i < PR_N4) outz[i] = 0.f;
}

// ---------------- fused scan (64 blocks) + embed (4096 blocks x 8 tokens) ----------
__global__ __launch_bounds__(512) void scan_embed(
    const int* __restrict__ x, const float* __restrict__ emb,
    const float* __restrict__ pos, short* __restrict__ hb,
    int* __restrict__ mask, int* __restrict__ logical,
    int* __restrict__ pol, int* __restrict__ nvalid) {
    if (blockIdx.x < 64) {
        int b = blockIdx.x, t = threadIdx.x;
        __shared__ int s[L_];
        int m = (x[b * L_ + t] != 0) ? 1 : 0;
        s[t] = m;
        __syncthreads();
        for (int off = 1; off < L_; off <<= 1) {
            int v = (t >= off) ? s[t - off] : 0;
            __syncthreads();
            s[t] += v;
            __syncthreads();
        }
        int cum = s[t];
        int lg = cum - 1; if (lg < 0) lg = 0;
        mask[b * L_ + t] = m;
        logical[b * L_ + t] = lg;
        if (m) pol[b * L_ + lg] = t;
        if (t == L_ - 1) nvalid[b] = cum;
    } else {
        int t = threadIdx.x & 255, sub = threadIdx.x >> 8;
        int blk2 = (blockIdx.x - 64) * 2 + sub;
        int bl = tok_swizzle(blk2) + (t >> 6);
        int lane = t & 63;
        int xv = x[bl];
        float mf = (xv != 0) ? 1.f : 0.f;
        int l = bl & (L_ - 1);
        float4 e = *(const float4*)&emb[(size_t)xv * C_ + lane * 4];
        float4 p = *(const float4*)&pos[(size_t)l * C_ + lane * 4];
        short4v hv4;
        hv4.x = f2bf((e.x + p.x * mf) * mf);
        hv4.y = f2bf((e.y + p.y * mf) * mf);
        hv4.z = f2bf((e.z + p.z * mf) * mf);
        hv4.w = f2bf((e.w + p.w * mf) * mf);
        *(short4v*)&hb[(size_t)bl * C_ + lane * 4] = hv4;
    }
}

// ---------------- deep-GEMM fragment helpers (shared) ----------
static __device__ __forceinline__ short8 lds_rd8(const short* p) {
    return *(const short8*)p;
}

template <int MH>
static __device__ __forceinline__ void ld_af(const short* bufA, int wm, int q, int t16,
                                             short8 af[4][2]) {
#pragma unroll
    for (int mfl = 0; mfl < 4; ++mfl) {
        int row = wm * 128 + (MH * 4 + mfl) * 16 + t16;
#pragma unroll
        for (int ks = 0; ks < 2; ++ks) {
            int cg = (ks * 4 + q) ^ (row & 7);
            af[mfl][ks] = lds_rd8(&bufA[row * 64 + cg * 8]);
        }
    }
}

template <int NH>
static __device__ __forceinline__ void ld_bf(const short* bufB, int wn, int q, int t16,
                                             short8 bf[2][2]) {
#pragma unroll
    for (int nfl = 0; nfl < 2; ++nfl) {
        int row = wn * 64 + (NH * 2 + nfl) * 16 + t16;
#pragma unroll
        for (int ks = 0; ks < 2; ++ks) {
            int cg = (ks * 4 + q) ^ (row & 7);
            bf[nfl][ks] = lds_rd8(&bufB[row * 64 + cg * 8]);
        }
    }
}

// B fragment read for BN=128 (wave covers 32 cols): rows wn*32 + nfl*16 + t16
static __device__ __forceinline__ void ld_bf32(const short* bufB, int wn, int q, int t16,
                                               short8 bf[2][2]) {
#pragma unroll
    for (int nfl = 0; nfl < 2; ++nfl) {
        int row = wn * 32 + nfl * 16 + t16;
#pragma unroll
        for (int ks = 0; ks < 2; ++ks) {
            int cg = (ks * 4 + q) ^ (row & 7);
            bf[nfl][ks] = lds_rd8(&bufB[row * 64 + cg * 8]);
        }
    }
}

template <int MH, int NH>
static __device__ __forceinline__ void mfma_q(const short8 af[4][2], const short8 bf[2][2],
                                              floatx4 acc[4][8]) {
    __builtin_amdgcn_s_setprio(1);
#pragma unroll
    for (int ks = 0; ks < 2; ++ks)
#pragma unroll
        for (int mfl = 0; mfl < 4; ++mfl)
#pragma unroll
            for (int nfl = 0; nfl < 2; ++nfl)
                acc[NH * 2 + nfl][MH * 4 + mfl] = __builtin_amdgcn_mfma_f32_16x16x32_bf16(
                    bf[nfl][ks], af[mfl][ks], acc[NH * 2 + nfl][MH * 4 + mfl], 0, 0, 0);
    __builtin_amdgcn_s_setprio(0);
}

template <int MH>
static __device__ __forceinline__ void mfma_m(const short8 af[4][2], const short8 bf[2][2],
                                              floatx4 acc[2][8]) {
    __builtin_amdgcn_s_setprio(1);
#pragma unroll
    for (int ks = 0; ks < 2; ++ks)
#pragma unroll
        for (int mfl = 0; mfl < 4; ++mfl)
#pragma unroll
            for (int nfl = 0; nfl < 2; ++nfl)
                acc[nfl][MH * 4 + mfl] = __builtin_amdgcn_mfma_f32_16x16x32_bf16(
                    bf[nfl][ks], af[mfl][ks], acc[nfl][MH * 4 + mfl], 0, 0, 0);
    __builtin_amdgcn_s_setprio(0);
}

// ---------------- projection + Ssd GEMM, deep 256x128 pipeline ----------
__global__ __launch_bounds__(512, 2) void projssd_deep(const short* __restrict__ A0,
                                                       const short* __restrict__ Bw,
                                                       short* __restrict__ hpb2,
                                                       float* __restrict__ Ssd) {
    __shared__ short lds[2][24576];   // per buf: A[256][64] @0, B[128][64] @16384
    const int id = blockIdx.x;
    const int j = id >> 3;                       // 0..79
    const int cb = j >> 4;                       // 0..4
    const int rb = (id & 7) * 16 + (j & 15);     // 0..127
    const int tid = threadIdx.x;
    const int wave = tid >> 6, lane = tid & 63;
    const int wm = wave >> 2, wn = wave & 3;
    const int q = lane >> 4, t16 = lane & 15;
    const size_t arow0 = (size_t)rb * 256;
    const short* Bb = Bw + (size_t)cb * 128 * 256;

    floatx4 acc[2][8];
#pragma unroll
    for (int i = 0; i < 2; i++)
#pragma unroll
        for (int jj = 0; jj < 8; jj++) acc[i][jj] = (floatx4)0.f;

    auto stageA = [&](int t, int Hh) {
        short* bufA = lds[t & 1];
#pragma unroll
        for (int u = 0; u < 2; ++u) {
            int unit = u * 512 + tid;
            int row = Hh * 128 + (unit >> 3);
            int cs = (unit & 7) ^ (row & 7);
            gl_lds16(A0 + (arow0 + (size_t)row) * 256 + t * 64 + cs * 8,
                     bufA + Hh * 8192 + unit * 8);
        }
    };
    auto stageB = [&](int t) {
        short* bufB = lds[t & 1] + 16384;
#pragma unroll
        for (int u = 0; u < 2; ++u) {
            int unit = u * 512 + tid;
            int row = unit >> 3;                 // 0..127
            int cs = (unit & 7) ^ (row & 7);
            gl_lds16(Bb + (size_t)row * 256 + t * 64 + cs * 8, bufB + unit * 8);
        }
    };

    stageA(0, 0); stageA(0, 1); stageB(0); stageB(1);
    asm volatile("s_waitcnt vmcnt(2)" ::: "memory");
    CF(); __builtin_amdgcn_s_barrier(); CF();

    short8 af[4][2], bfr[2][2];

#pragma unroll
    for (int t = 0; t < 4; ++t) {
        const short* bufA = lds[t & 1];
        const short* bufB = lds[t & 1] + 16384;

        ld_af<0>(bufA, wm, q, t16, af);
        ld_bf32(bufB, wn, q, t16, bfr);
        if (t < 3) { stageA(t + 1, 0); stageA(t + 1, 1); }
        CF(); __builtin_amdgcn_s_barrier();
        asm volatile("s_waitcnt lgkmcnt(0)" ::: "memory");
        __builtin_amdgcn_sched_barrier(0);
        mfma_m<0>(af, bfr, acc);
        CF(); __builtin_amdgcn_s_barrier(); CF();

        ld_af<1>(bufA, wm, q, t16, af);
        if (t < 2) stageB(t + 2);
        CF(); __builtin_amdgcn_s_barrier();
        asm volatile("s_waitcnt lgkmcnt(0)" ::: "memory");
        __builtin_amdgcn_sched_barrier(0);
        mfma_m<1>(af, bfr, acc);
        if (t < 2)       asm volatile("s_waitcnt vmcnt(2)" ::: "memory");
        else if (t == 2) asm volatile("s_waitcnt vmcnt(0)" ::: "memory");
        CF(); __builtin_amdgcn_s_barrier(); CF();
    }

    if (cb < 4) {
        short* sO = (short*)lds;                 // [256][132]
#pragma unroll
        for (int nf = 0; nf < 2; nf++) {
            int chl = wn * 32 + nf * 16 + q * 4; // 0..127 within block
#pragma unroll
            for (int mf = 0; mf < 8; mf++) {
                int rowl = wm * 128 + mf * 16 + t16;
                short4v pk;
                pk.x = f2bf(acc[nf][mf][0]);
                pk.y = f2bf(acc[nf][mf][1]);
                pk.z = f2bf(acc[nf][mf][2]);
                pk.w = f2bf(acc[nf][mf][3]);
                *(short4v*)&sO[rowl * 132 + chl] = pk;
            }
        }
        __syncthreads();
#pragma unroll
        for (int it = 0; it < 8; ++it) {
            int unit = it * 512 + tid;
            int rowl = unit >> 4, ck = unit & 15;
            *(short8*)&hpb2[(arow0 + rowl) * 512 + cb * 128 + ck * 8] =
                *(const short8*)&sO[rowl * 132 + ck * 8];
        }
    } else {
        if (wn == 0) {
            int chl = q * 4;
            if (chl < 16) {
#pragma unroll
                for (int mf = 0; mf < 8; mf++) {
                    int rowl = wm * 128 + mf * 16 + t16;
                    float4 pk = make_float4(acc[0][mf][0], acc[0][mf][1],
                                            acc[0][mf][2], acc[0][mf][3]);
                    *(float4*)&Ssd[(arow0 + rowl) * 16 + chl] = pk;
                }
            }
        }
    }
}

// ---------------- dedicated GRU GEMM, 256x256 tile, 8-phase deep-vmcnt ----------
// (measured-good: BK=64, 1 block/CU, full unroll + sched_barrier, vmcnt(8))
__global__ __launch_bounds__(512, 2) void gru_bgemm(const short* __restrict__ mmb,
                                                    const short* __restrict__ hb_in,
                                                    const short* __restrict__ Bw,
                                                    short* __restrict__ hn2b,
                                                    const float* __restrict__ bias4) {
    __shared__ short lds[2][32768];   // per buf: A[256][64] @0, B[256][64] @16384
    const int id = blockIdx.x;
    const int rb = 16 * (id & 7) + (id >> 5);
    const int cb = (id >> 3) & 3;
    const int tid = threadIdx.x;
    const int wave = tid >> 6, lane = tid & 63;
    const int wm = wave >> 2, wn = wave & 3;
    const int q = lane >> 4, t16 = lane & 15;
    const size_t arow0 = (size_t)rb * 256;
    const short* Bb = Bw + (size_t)cb * 256 * 512;
    const int ord0 = (5 + cb) & 7;

    floatx4 acc[4][8];   // [nf][mf]
#pragma unroll
    for (int i = 0; i < 4; i++)
#pragma unroll
        for (int jj = 0; jj < 8; jj++) acc[i][jj] = (floatx4)0.f;

    auto stageA = [&](int i, int Hh) {
        int tt = (ord0 + i) & 7;
        const short* Asrc = (tt < 4) ? (mmb + tt * 64) : (hb_in + (tt - 4) * 64);
        short* bufA = lds[i & 1];
#pragma unroll
        for (int u = 0; u < 2; ++u) {
            int unit = u * 512 + tid;              // 0..1023
            int row = Hh * 128 + (unit >> 3);
            int cs = (unit & 7) ^ (row & 7);
            gl_lds16(Asrc + (arow0 + (size_t)row) * 256 + cs * 8,
                     bufA + Hh * 8192 + unit * 8);
        }
    };
    auto stageB = [&](int i, int Hh) {
        int tt = (ord0 + i) & 7;
        short* bufB = lds[i & 1] + 16384;
#pragma unroll
        for (int u = 0; u < 2; ++u) {
            int unit = u * 512 + tid;
            int row = Hh * 128 + (unit >> 3);
            int cs = (unit & 7) ^ (row & 7);
            gl_lds16(Bb + (size_t)row * 512 + tt * 64 + cs * 8,
                     bufB + Hh * 8192 + unit * 8);
        }
    };

    // prologue: tiles 0 and 1 fully issued (16 loads/wave);
    // vmcnt(8): tile 0 complete, tile 1's 8 loads stay in flight
    stageA(0, 0); stageA(0, 1); stageB(0, 0); stageB(0, 1);
    stageA(1, 0); stageA(1, 1); stageB(1, 0); stageB(1, 1);
    asm volatile("s_waitcnt vmcnt(8)" ::: "memory");
    CF(); __builtin_amdgcn_s_barrier(); CF();

    short8 af[4][2], b0[2][2], b1[2][2];

#pragma unroll
    for (int t = 0; t < 8; ++t) {
        const short* bufA = lds[t & 1];
        const short* bufB = lds[t & 1] + 16384;

        // ---- P0: quadrant (0,0) ----
        ld_af<0>(bufA, wm, q, t16, af);
        ld_bf<0>(bufB, wn, q, t16, b0);
        CF(); __builtin_amdgcn_s_barrier();
        asm volatile("s_waitcnt lgkmcnt(0)" ::: "memory");
        __builtin_amdgcn_sched_barrier(0);
        mfma_q<0, 0>(af, b0, acc);
        CF(); __builtin_amdgcn_s_barrier(); CF();

        // ---- P1: quadrant (0,1) ----
        ld_bf<1>(bufB, wn, q, t16, b1);
        CF(); __builtin_amdgcn_s_barrier();
        asm volatile("s_waitcnt lgkmcnt(0)" ::: "memory");
        __builtin_amdgcn_sched_barrier(0);
        mfma_q<0, 1>(af, b1, acc);
        CF(); __builtin_amdgcn_s_barrier(); CF();

        // ---- P2: quadrant (1,1) ----  (bufB[t&1] free after P1's end barrier)
        ld_af<1>(bufA, wm, q, t16, af);
        if (t < 6) { stageB(t + 2, 0); stageB(t + 2, 1); }
        CF(); __builtin_amdgcn_s_barrier();
        asm volatile("s_waitcnt lgkmcnt(0)" ::: "memory");
        __builtin_amdgcn_sched_barrier(0);
        mfma_q<1, 1>(af, b1, acc);
        CF(); __builtin_amdgcn_s_barrier(); CF();

        // ---- P3: quadrant (1,0) ----  (bufA[t&1] free after P2's end barrier)
        if (t < 6) { stageA(t + 2, 0); stageA(t + 2, 1); }
        CF(); __builtin_amdgcn_s_barrier();
        mfma_q<1, 0>(af, b0, acc);
        // tile boundary: su(t+1) (oldest 8) complete; su(t+2) (8) stay in flight
        if (t < 6)       asm volatile("s_waitcnt vmcnt(8)" ::: "memory");
        else if (t == 6) asm volatile("s_waitcnt vmcnt(0)" ::: "memory");
        CF(); __builtin_amdgcn_s_barrier(); CF();
    }

    // epilogue: h_prev from LDS (lds[1] holds A-tile of tt=4+cb = hb cols cb*64..),
    // compute gates, stage hn2 tile in LDS, coalesced bf16 write.
    const short* hpt = lds[1];
    short* sO = (short*)lds;                   // [256][72] bf16 within lds[0]
#pragma unroll
    for (int nf = 0; nf < 4; nf++) {
        int chl = wn * 16 + nf * 4 + q;        // 0..63 within block
        int col0 = cb * 256 + wn * 64 + nf * 16 + q * 4;
        float4 bv4 = *(const float4*)&bias4[col0];
#pragma unroll
        for (int mf = 0; mf < 8; mf++) {
            int rowl = wm * 128 + mf * 16 + t16;
            float hp = bf2f(hpt[rowl * 64 + (((chl >> 3) ^ (rowl & 7)) << 3) + (chl & 7)]);
            float r = sig_(acc[nf][mf][0] + bv4.x);
            float z = sig_(acc[nf][mf][1] + bv4.y);
            float nv = tanh_((acc[nf][mf][2] + bv4.z) + r * (acc[nf][mf][3] + bv4.w));
            sO[rowl * 72 + chl] = f2bf((1.f - z) * nv + z * hp);
        }
    }
    __syncthreads();
#pragma unroll
    for (int it = 0; it < 4; ++it) {
        int unit = it * 512 + tid;
        int rowl = unit >> 3, ck = unit & 7;
        *(short8*)&hn2b[(arow0 + rowl) * 256 + cb * 64 + ck * 8] =
            *(const short8*)&sO[rowl * 72 + ck * 8];
    }
}

// ---------------- msg GEMM, 256x128 tile, deep pipeline ----------
__global__ __launch_bounds__(512, 2) void msg_bgemm(const short* __restrict__ A0,
                                                    const short* __restrict__ Bw,
                                                    short* __restrict__ Cout,
                                                    const float* __restrict__ bias) {
    __shared__ short lds[2][24576];   // per buf: A[256][64] @0, B[128][64] @16384
    const int id = blockIdx.x;
    const int j = id >> 3;                       // 0..31
    const int rb = (id & 7) * 16 + (j & 15);     // 0..127
    const int cb = j >> 4;                       // 0..1
    const int tid = threadIdx.x;
    const int wave = tid >> 6, lane = tid & 63;
    const int wm = wave >> 2, wn = wave & 3;
    const int q = lane >> 4, t16 = lane & 15;
    const size_t arow0 = (size_t)rb * 256;
    const short* Bb = Bw + (size_t)cb * 128 * 512;

    floatx4 acc[2][8];
#pragma unroll
    for (int i = 0; i < 2; i++)
#pragma unroll
        for (int jj = 0; jj < 8; jj++) acc[i][jj] = (floatx4)0.f;

    auto stageA = [&](int t, int Hh) {
        short* bufA = lds[t & 1];
#pragma unroll
        for (int u = 0; u < 2; ++u) {
            int unit = u * 512 + tid;
            int row = Hh * 128 + (unit >> 3);
            int cs = (unit & 7) ^ (row & 7);
            gl_lds16(A0 + (arow0 + (size_t)row) * 512 + t * 64 + cs * 8,
                     bufA + Hh * 8192 + unit * 8);
        }
    };
    auto stageB = [&](int t) {
        short* bufB = lds[t & 1] + 16384;
#pragma unroll
        for (int u = 0; u < 2; ++u) {
            int unit = u * 512 + tid;
            int row = unit >> 3;                 // 0..127
            int cs = (unit & 7) ^ (row & 7);
            gl_lds16(Bb + (size_t)row * 512 + t * 64 + cs * 8, bufB + unit * 8);
        }
    };

    stageA(0, 0); stageA(0, 1); stageB(0); stageB(1);
    asm volatile("s_waitcnt vmcnt(2)" ::: "memory");
    CF(); __builtin_amdgcn_s_barrier(); CF();

    short8 af[4][2], bfr[2][2];

#pragma unroll 2
    for (int t = 0; t < 8; ++t) {
        const short* bufA = lds[t & 1];
        const short* bufB = lds[t & 1] + 16384;

        ld_af<0>(bufA, wm, q, t16, af);
        ld_bf32(bufB, wn, q, t16, bfr);
        if (t < 7) { stageA(t + 1, 0); stageA(t + 1, 1); }
        CF(); __builtin_amdgcn_s_barrier();
        asm volatile("s_waitcnt lgkmcnt(0)" ::: "memory");
        mfma_m<0>(af, bfr, acc);
        CF(); __builtin_amdgcn_s_barrier(); CF();

        ld_af<1>(bufA, wm, q, t16, af);
        if (t < 6) stageB(t + 2);
        CF(); __builtin_amdgcn_s_barrier();
        asm volatile("s_waitcnt lgkmcnt(0)" ::: "memory");
        mfma_m<1>(af, bfr, acc);
        if (t < 6)       asm volatile("s_waitcnt vmcnt(2)" ::: "memory");
        else if (t == 6) asm volatile("s_waitcnt vmcnt(0)" ::: "memory");
        CF(); __builtin_amdgcn_s_barrier(); CF();
    }

    // epilogue: bias + relu + bf16, LDS-staged coalesced write
    short* sO = (short*)lds;                     // [256][132]
#pragma unroll
    for (int nf = 0; nf < 2; nf++) {
        int chl = wn * 32 + nf * 16 + q * 4;     // 0..127 within block
        int col0 = cb * 128 + chl;
        float4 bv4 = *(const float4*)&bias[col0];
#pragma unroll
        for (int mf = 0; mf < 8; mf++) {
            int rowl = wm * 128 + mf * 16 + t16;
            short4v pk;
            pk.x = f2bf(fmaxf(acc[nf][mf][0] + bv4.x, 0.f));
            pk.y = f2bf(fmaxf(acc[nf][mf][1] + bv4.y, 0.f));
            pk.z = f2bf(fmaxf(acc[nf][mf][2] + bv4.z, 0.f));
            pk.w = f2bf(fmaxf(acc[nf][mf][3] + bv4.w, 0.f));
            *(short4v*)&sO[rowl * 132 + chl] = pk;
        }
    }
    __syncthreads();
#pragma unroll
    for (int it = 0; it < 8; ++it) {
        int unit = it * 512 + tid;
        int rowl = unit >> 4, ck = unit & 15;
        *(short8*)&Cout[(arow0 + rowl) * 256 + cb * 128 + ck * 8] =
            *(const short8*)&sO[rowl * 132 + ck * 8];
    }
}

// ---------------- LayerNorm over hn2 (bf16) + mask -> hb (layers 0,1 only) ------
__global__ __launch_bounds__(256) void ln_kernel(
    const short* __restrict__ hn2b, short* __restrict__ hb,
    const int* __restrict__ mask,
    const float* __restrict__ lng, const float* __restrict__ lnb) {
    int t = threadIdx.x;
    int bl = tok_swizzle(blockIdx.x) + (t >> 6);
    int lane = t & 63;
    short4v v4 = *(const short4v*)&hn2b[(size_t)bl * C_ + lane * 4];
    float v[4] = {bf2f(v4.x), bf2f(v4.y), bf2f(v4.z), bf2f(v4.w)};
    float s = (v[0] + v[1]) + (v[2] + v[3]);
    float ss = (v[0] * v[0] + v[1] * v[1]) + (v[2] * v[2] + v[3] * v[3]);
#pragma unroll
    for (int off = 32; off; off >>= 1) {
        s += __shfl_xor(s, off);
        ss += __shfl_xor(ss, off);
    }
    float mu = s * (1.f / 256.f);
    float var = ss * (1.f / 256.f) - mu * mu;
    float rstd = rsqrtf(fmaxf(var, 0.f) + 1e-5f);
    float4 lg = *(const float4*)&lng[lane * 4];
    float4 lb = *(const float4*)&lnb[lane * 4];
    float mfv = mask[bl] ? 1.f : 0.f;
    short4v yb;
    yb.x = f2bf(((v[0] - mu) * rstd * lg.x + lb.x) * mfv);
    yb.y = f2bf(((v[1] - mu) * rstd * lg.y + lb.y) * mfv);
    yb.z = f2bf(((v[2] - mu) * rstd * lg.z + lb.z) * mfv);
    yb.w = f2bf(((v[3] - mu) * rstd * lg.w + lb.w) * mfv);
    *(short4v*)&hb[(size_t)bl * C_ + lane * 4] = yb;
}

// ---------------- sparse GAT aggregation, vectorized short8, both dirs ----------------
// (measured-good tok_swizzle mapping)
__global__ __launch_bounds__(256) void agg_fused(
    const short* __restrict__ hpb2, const float* __restrict__ S,
    const int* __restrict__ mask, const int* __restrict__ logical,
    const int* __restrict__ pol, const int* __restrict__ nvalid,
    short* __restrict__ m, int dil) {
    int t = threadIdx.x;
    int bl = tok_swizzle(blockIdx.x) + (t >> 6);
    int sub = t & 63;
    int dir = sub >> 5;
    int slot = sub & 31;
    int cb = slot * 8;
    int head = slot >> 3;
    int b = bl >> 9;

    int mi = mask[bl];
    int li = logical[bl];
    int nv = nvalid[b];
    int js[3]; int nn = 0;
    if (mi) {
#pragma unroll
        for (int k = 1; k <= 3; k++) {
            int lj = dir ? (li - k * dil) : (li + k * dil);
            if (lj >= 0 && lj < nv) js[nn++] = pol[b * L_ + lj];
        }
    }
    int sn = dir * 4 + head, dn = 8 + sn;
    float si = S[(size_t)bl * 16 + sn];
    float di = S[(size_t)bl * 16 + dn];
    float e0 = si + di; e0 = e0 > 0.f ? e0 : 0.2f * e0;
    float emax = e0, ev[3];
    for (int k = 0; k < nn; k++) {
        float djv = S[((size_t)(b * L_ + js[k])) * 16 + dn];
        float e = si + djv; e = e > 0.f ? e : 0.2f * e;
        ev[k] = e; emax = fmaxf(emax, e);
    }
    float w0 = __expf(e0 - emax), den = w0;
    float wv[3];
    for (int k = 0; k < nn; k++) { wv[k] = __expf(ev[k] - emax); den += wv[k]; }
    float rden = rcp_(den);

    size_t base = (size_t)bl * 512 + dir * 256 + cb;
    short8 vself = *(const short8*)&hpb2[base];
    float o[8];
#pragma unroll
    for (int j = 0; j < 8; j++) o[j] = w0 * bf2f(vself[j]);
    for (int k = 0; k < nn; k++) {
        short8 vn = *(const short8*)&hpb2[((size_t)(b * L_ + js[k])) * 512 + dir * 256 + cb];
#pragma unroll
        for (int j = 0; j < 8; j++) o[j] = fmaf(wv[k], bf2f(vn[j]), o[j]);
    }
    short8 ov;
#pragma unroll
    for (int j = 0; j < 8; j++) ov[j] = f2bf(o[j] * rden);
    *(short8*)&m[base] = ov;
}

// ---------------- per-row score + LN stats (wave per token, 32K-wave TLP) --------
// scW[tok] = masked pooled-attention score with layer-2 LN folded (affine form);
// muW/rsW = per-row LN stats for the pooled-sum transform in pool_head_ln2.
__global__ __launch_bounds__(256) void score_ln_kernel(
    const short* __restrict__ hn2b, const int* __restrict__ mask,
    const float* __restrict__ pw, const float* __restrict__ pb,
    const float* __restrict__ lng2, const float* __restrict__ lnb2,
    float* __restrict__ scW, float* __restrict__ muW, float* __restrict__ rsW) {
    int t = threadIdx.x;
    int bl = tok_swizzle(blockIdx.x) + (t >> 6);
    int lane = t & 63;
    short4v hv = *(const short4v*)&hn2b[(size_t)bl * C_ + lane * 4];
    float4 wv = *(const float4*)&pw[lane * 4];
    float4 gv = *(const float4*)&lng2[lane * 4];
    float4 bv = *(const float4*)&lnb2[lane * 4];
    float h0 = bf2f(hv.x), h1 = bf2f(hv.y), h2 = bf2f(hv.z), h3 = bf2f(hv.w);
    float pg0 = wv.x * gv.x, pg1 = wv.y * gv.y, pg2 = wv.z * gv.z, pg3 = wv.w * gv.w;
    float s1 = pg0 * h0 + pg1 * h1 + pg2 * h2 + pg3 * h3;
    float s2 = (h0 + h1) + (h2 + h3);
    float s3 = (h0 * h0 + h1 * h1) + (h2 * h2 + h3 * h3);
    float cg = (pg0 + pg1) + (pg2 + pg3);
    float cb = (wv.x * bv.x + wv.y * bv.y) + (wv.z * bv.z + wv.w * bv.w);
#pragma unroll
    for (int off = 32; off; off >>= 1) {
        s1 += __shfl_xor(s1, off);
        s2 += __shfl_xor(s2, off);
        s3 += __shfl_xor(s3, off);
        cg += __shfl_xor(cg, off);
        cb += __shfl_xor(cb, off);
    }
    if (lane == 0) {
        float mu = s2 * (1.f / 256.f);
        float var = s3 * (1.f / 256.f) - mu * mu;
        float rstd = rsqrtf(fmaxf(var, 0.f) + 1e-5f);
        int mk = mask[bl];
        scW[bl] = mk ? (rstd * (s1 - mu * cg) + cb + pb[0]) : NEGV;
        muW[bl] = mu;
        rsW[bl] = mk ? rstd : 0.f;
    }
}

// ---------------- pooling + heads from precomputed scores ----------------
// Grid 256 = b*4 + s. Softmax over scW (no hn2b re-read); weighted slice sum;
// layer-2 LN transform on the pooled vector; heads via atomicAdd (out zeroed
// in prep_all). pooled[c] = gamma_c*(sum_l arv_l*h[l,c] - S_amu) + beta_c.
__global__ __launch_bounds__(1024) void pool_head_ln2(
    const short* __restrict__ hn2b,
    const float* __restrict__ scW, const float* __restrict__ muW,
    const float* __restrict__ rsW,
    const float* __restrict__ lng2, const float* __restrict__ lnb2,
    const float* __restrict__ h0W, const float* __restrict__ h0b,
    const float* __restrict__ h1W, const float* __restrict__ h1b,
    float* __restrict__ out) {
    int b = blockIdx.x >> 2, s = blockIdx.x & 3;
    int t = threadIdx.x;
    int lane = t & 63, wave = t >> 6;
    __shared__ float sc[L_];
    __shared__ float red[24];
    __shared__ float part[16][64];
    __shared__ float pooled[64];

    // softmax over 512 precomputed scores
    float v = (t < L_) ? scW[b * L_ + t] : NEGV;
    float mx = v;
#pragma unroll
    for (int off = 32; off; off >>= 1) mx = fmaxf(mx, __shfl_down(mx, off));
    if (lane == 0) red[wave] = mx;
    __syncthreads();
    if (t == 0) {
        float g = red[0];
        for (int i = 1; i < 16; i++) g = fmaxf(g, red[i]);
        red[16] = g;
    }
    __syncthreads();
    float gmax = red[16];
    float e = (t < L_) ? __expf(v - gmax) : 0.f;
    float ssum = e;
#pragma unroll
    for (int off = 32; off; off >>= 1) ssum += __shfl_down(ssum, off);
    if (lane == 0) red[wave] = ssum;
    __syncthreads();
    if (t == 0) {
        float g = 0.f;
        for (int i = 0; i < 16; i++) g += red[i];
        red[17] = 1.f / g;
    }
    __syncthreads();
    float a = e * red[17];
    float arv = (t < L_) ? a * rsW[b * L_ + t] : 0.f;
    float amu = (t < L_) ? arv * muW[b * L_ + t] : 0.f;
    if (t < L_) sc[t] = arv;
#pragma unroll
    for (int off = 32; off; off >>= 1) amu += __shfl_down(amu, off);
    if (lane == 0) red[wave] = amu;
    __syncthreads();
    if (t == 0) {
        float g = 0.f;
        for (int i = 0; i < 16; i++) g += red[i];
        red[18] = g;
    }
    __syncthreads();

    // pass 2: weighted raw sum over this block's 64-ch slice, then LN transform
    {
        int c0 = t & 63, lw = t >> 6;
        const short* hcol = &hn2b[((size_t)b * L_ + lw * 32) * C_ + s * 64 + c0];
        const float* scg = &sc[lw * 32];
        float a0 = 0.f, a1 = 0.f;
        for (int l = 0; l < 32; l += 2) {
            a0 = fmaf(scg[l + 0], bf2f(hcol[(size_t)(l + 0) * C_]), a0);
            a1 = fmaf(scg[l + 1], bf2f(hcol[(size_t)(l + 1) * C_]), a1);
        }
        part[lw][c0] = a0 + a1;
    }
    __syncthreads();
    if (t < 64) {
        float p = 0.f;
        for (int i = 0; i < 16; i++) p += part[i][t];
        int c = s * 64 + t;
        pooled[t] = lng2[c] * (p - red[18]) + lnb2[c];
    }
    __syncthreads();

    // pass 3: head partials over this 64-ch slice, atomicAdd to out
    for (int o = wave; o < 70; o += 16) {
        const float* W = (o < 50) ? (h0W + (size_t)o * C_) : (h1W + (size_t)(o - 50) * C_);
        float sv = pooled[lane] * W[s * 64 + lane];
#pragma unroll
        for (int off = 32; off; off >>= 1) sv += __shfl_down(sv, off);
        if (lane == 0) {
            float add = sv + ((s == 0) ? ((o < 50) ? h0b[o] : h1b[o - 50]) : 0.f);
            atomicAdd(&out[b * 70 + o], add);
        }
    }
}

extern "C" void kernel_launch(void* const* d_in, const int* in_sizes, int n_in,
                              void* d_out, int out_size, void* d_ws, size_t ws_size,
                              hipStream_t stream) {
    const int*   x    = (const int*)d_in[0];
    const float* emb  = (const float*)d_in[1];
    const float* pos  = (const float*)d_in[2];
    const float* gpW  = (const float*)d_in[3];
    const float* gpas = (const float*)d_in[4];
    const float* gpad = (const float*)d_in[5];
    const float* gfW  = (const float*)d_in[6];
    const float* gfas = (const float*)d_in[7];
    const float* gfad = (const float*)d_in[8];
    const float* msgW = (const float*)d_in[9];
    const float* msgb = (const float*)d_in[10];
    const float* Wih  = (const float*)d_in[11];
    const float* bih  = (const float*)d_in[12];
    const float* Whh  = (const float*)d_in[13];
    const float* bhh  = (const float*)d_in[14];
    const float* lng  = (const float*)d_in[15];
    const float* lnb  = (const float*)d_in[16];
    const float* pw   = (const float*)d_in[17];
    const float* pb   = (const float*)d_in[18];
    const float* h0W  = (const float*)d_in[19];
    const float* h0b  = (const float*)d_in[20];
    const float* h1W  = (const float*)d_in[21];
    const float* h1b  = (const float*)d_in[22];
    float* out = (float*)d_out;

    const size_t MW = 1024 * 1024;
    float* ws = (float*)d_ws;
    short* hn2b = (short*)ws;
    short* hb   = (short*)(ws + 8 * MW);
    short* mmb  = (short*)(ws + 12 * MW);
    float* Ssd  = ws + 12 * MW;                          // aliases mmb (timeshared)
    short* hpb2 = (short*)(ws + 16 * MW);
    short* mb   = (short*)(ws + 24 * MW);
    short* Wcomb = (short*)(ws + 32 * MW);               // 3*640*256 shorts
    short* msgWb = Wcomb + 3 * 640 * 256;                // 3*256*512 shorts
    short* Bcat  = msgWb + 3 * 256 * 512;                // 3*1024*512 shorts (interleaved)
    float* bias4 = (float*)(Bcat + 3 * 1024 * 512);      // 3*1024 floats
    int* mask    = (int*)(bias4 + 3 * 1024);
    int* logical = mask + B_ * L_;
    int* pol     = logical + B_ * L_;
    int* nvalid  = pol + B_ * L_;
    float* scW   = (float*)(nvalid + B_);                // 32768 floats
    float* muW   = scW + B_ * L_;
    float* rsW   = muW + B_ * L_;

    prep_all<<<(PR_TOT + 255) / 256, 256, 0, stream>>>(
        gpW, gfW, gpas, gpad, gfas, gfad, msgW, Wih, Whh, bih, bhh,
        Wcomb, msgWb, Bcat, bias4, out);

    scan_embed<<<64 + 4096, 512, 0, stream>>>(x, emb, pos, hb, mask, logical, pol, nvalid);

    const int DILS[LAY] = {1, 2, 4};

    for (int l = 0; l < LAY; l++) {
        int dil = DILS[l];
        projssd_deep<<<640, 512, 0, stream>>>(hb, Wcomb + (size_t)l * 640 * 256,
                                              hpb2, Ssd);
        agg_fused<<<8192, 256, 0, stream>>>(hpb2, Ssd, mask, logical, pol, nvalid, mb, dil);
        msg_bgemm<<<256, 512, 0, stream>>>(mb, msgWb + (size_t)l * 256 * 512,
                                           mmb, msgb + l * C_);
        gru_bgemm<<<512, 512, 0, stream>>>(mmb, hb, Bcat + (size_t)l * 1024 * 512,
                                           hn2b, bias4 + l * 1024);
        if (l < 2)
            ln_kernel<<<8192, 256, 0, stream>>>(hn2b, hb, mask, lng + l * C_, lnb + l * C_);
    }

    // per-row scores + LN stats (32K waves), then pooling + heads from them
    score_ln_kernel<<<8192, 256, 0, stream>>>(hn2b, mask, pw, pb,
                                              lng + 2 * C_, lnb + 2 * C_,
                                              scW, muW, rsW);
    pool_head_ln2<<<B_ * 4, 1024, 0, stream>>>(hn2b, scW, muW, rsW,
                                               lng + 2 * C_, lnb + 2 * C_,
                                               h0W, h0b, h1W, h1b, out);
}